// Round 10
// baseline (519.336 us; speedup 1.0000x reference)
//
#include <hip/hip_runtime.h>
#include <hip/hip_fp16.h>

#define NN 100000
#define EE 1600000
#define DD 32
#define CC 2
#define NLAYERS 4
#define GG 512

#define BSH 9                         // log2(nodes per dst-bucket)
#define BW 512                        // nodes per dst-bucket
#define NBUK ((NN + BW - 1) / BW)     // 196
#define CAP 12288                     // per-bucket staging capacity (mean 8163)
#define CH 2048                       // edges per partition block
#define NPART ((EE + CH - 1) / CH)    // 782

// ---------------------------------------------------------------------------
// Phase 1: partition edges into NBUK dst-range buckets. LDS-staged so the
// global writes are coalesced runs. Packs (dst_local<<17 | src) into 4B.
// ---------------------------------------------------------------------------
__global__ void part_kernel(const int* __restrict__ ei,
                            int* __restrict__ gcur,
                            unsigned* __restrict__ part) {
    __shared__ unsigned sorted[CH];        // 8 KB
    __shared__ unsigned char sbkt[CH];     // 2 KB
    __shared__ int cnt[NBUK], offs[NBUK], cur[NBUK], gbs[NBUK];

    const int tid = threadIdx.x;
    const int eb  = blockIdx.x * CH;
    const int nch = min(CH, EE - eb);

    for (int b = tid; b < NBUK; b += 256) cnt[b] = 0;
    __syncthreads();
    for (int i = tid; i < nch; i += 256) {
        int dn = ei[EE + eb + i];
        atomicAdd(&cnt[dn >> BSH], 1);
    }
    __syncthreads();
    if (tid == 0) {
        int o = 0;
        for (int b = 0; b < NBUK; ++b) { offs[b] = o; o += cnt[b]; }
    }
    __syncthreads();
    if (tid < NBUK) {
        cur[tid] = offs[tid];
        gbs[tid] = cnt[tid] ? atomicAdd(&gcur[tid], cnt[tid]) : 0;
    }
    __syncthreads();
    for (int i = tid; i < nch; i += 256) {
        int s  = ei[eb + i];
        int dn = ei[EE + eb + i];
        int b  = dn >> BSH;
        unsigned pk = ((unsigned)(dn & (BW - 1)) << 17) | (unsigned)s;
        int p = atomicAdd(&cur[b], 1);
        sorted[p] = pk;
        sbkt[p]   = (unsigned char)b;
    }
    __syncthreads();
    for (int i = tid; i < nch; i += 256) {
        int b = sbkt[i];
        part[(size_t)b * CAP + gbs[b] + (i - offs[b])] = sorted[i];
    }
}

// Phase 2: exclusive scan of 196 bucket counts (trivial).
__global__ void bscan_kernel(const int* __restrict__ gcur,
                             int* __restrict__ bbase,
                             int* __restrict__ row_ptr) {
    if (threadIdx.x == 0 && blockIdx.x == 0) {
        int o = 0;
        for (int b = 0; b < NBUK; ++b) { bbase[b] = o; o += gcur[b]; }
        row_ptr[NN] = EE;
    }
}

// ---------------------------------------------------------------------------
// Phase 3: per-bucket local CSR. Histogram + scan of 512 nodes in LDS; fill
// writes land in one contiguous ~32KB region -> L2-resident, no write amp.
// ---------------------------------------------------------------------------
__global__ void lcsr_kernel(const unsigned* __restrict__ part,
                            const int* __restrict__ gcur,
                            const int* __restrict__ bbase,
                            int* __restrict__ row_ptr,
                            int* __restrict__ csr_src) {
    __shared__ int hcnt[BW];
    __shared__ int a[2][BW];
    __shared__ int ccur[BW];
    const int t    = threadIdx.x;
    const int b    = blockIdx.x;
    const int cntb = gcur[b];
    const int base = bbase[b];
    const size_t pb = (size_t)b * CAP;

    hcnt[t] = 0;
    __syncthreads();
    for (int i = t; i < cntb; i += BW)
        atomicAdd(&hcnt[part[pb + i] >> 17], 1);
    __syncthreads();
    int x = hcnt[t];
    a[0][t] = x;
    __syncthreads();
    int cb = 0;
    for (int off = 1; off < BW; off <<= 1) {
        int v = a[cb][t];
        if (t >= off) v += a[cb][t - off];
        a[cb ^ 1][t] = v;
        cb ^= 1;
        __syncthreads();
    }
    const int excl = a[cb][t] - x;
    const int node = b * BW + t;
    if (node < NN) row_ptr[node] = base + excl;
    ccur[t] = excl;
    __syncthreads();
    for (int i = t; i < cntb; i += BW) {
        unsigned pk = part[pb + i];
        int dl  = pk >> 17;
        int pos = base + atomicAdd(&ccur[dl], 1);
        csr_src[pos] = (int)(pk & 0x1FFFFu);
    }
}

// ---------------------------------------------------------------------------
// Fused level-0 pool + f32->fp16 convert (single pass over node_emb).
// ---------------------------------------------------------------------------
__global__ void pool_cvt_kernel(const float* __restrict__ h,
                                const int* __restrict__ batch,
                                const float* __restrict__ Wd,
                                float* __restrict__ score,
                                __half* __restrict__ h16) {
    __shared__ float ss[GG * CC];
    __shared__ float sW[DD * CC];
    const int tid = threadIdx.x;
    for (int i = tid; i < GG * CC; i += 256) ss[i] = 0.f;
    if (tid < DD * CC) sW[tid] = Wd[tid];
    __syncthreads();

    const int d = tid & 31;
    const int grp = tid >> 5;
    const int n0 = blockIdx.x * 512;
    const int n1 = (n0 + 512 < NN) ? (n0 + 512) : NN;

    for (int n = n0 + grp; n < n1; n += 8) {
        float v = h[(size_t)n * DD + d];
        h16[(size_t)n * DD + d] = __float2half_rn(v);
        float p0 = v * sW[d * CC + 0];
        float p1 = v * sW[d * CC + 1];
        #pragma unroll
        for (int off = 16; off > 0; off >>= 1) {
            p0 += __shfl_xor(p0, off, 32);
            p1 += __shfl_xor(p1, off, 32);
        }
        if (d == 0) {
            int g = batch[n];
            atomicAdd(&ss[g * CC + 0], p0);
            atomicAdd(&ss[g * CC + 1], p1);
        }
    }
    __syncthreads();

    for (int i = tid; i < GG * CC; i += 256) {
        float v = ss[i];
        if (v != 0.f) atomicAdd(&score[i], v);
    }
}

// ---------------------------------------------------------------------------
// Fused GIN layer. r9's counters (fp16 halved FETCH, time unchanged; ILP x2
// and waves x2 also null) => gather is VMEM-INSTRUCTION bound (~2 instr/edge).
// Phase 1 rebuilt wave-cooperative: whole wave64 works ONE node; lane =
// (edge-slot lid>>3, dim-slice lid&7); one uint2 (8B = 4 halves) load per
// lane => ONE instruction fetches 8 full 64B fp16 rows (512B coalesced).
// ~0.6M VMEM instr/layer vs 3.3M. Finish: 3-round shfl_xor (8/16/32) on 4
// f32 accs, lanes 0..7 add self row + write zA row. No wave divergence
// (uniform trip count per node). Phase 2 (MLP+pool, proven) unchanged.
// ---------------------------------------------------------------------------
__global__ __launch_bounds__(256) void layer_kernel(
    const __half* __restrict__ h_in, __half* __restrict__ h_out,
    const int* __restrict__ row_ptr, const int* __restrict__ csr_src,
    const int* __restrict__ batch,
    const float* __restrict__ W1, const float* __restrict__ b1,
    const float* __restrict__ g1, const float* __restrict__ bt1,
    const float* __restrict__ W2, const float* __restrict__ b2,
    const float* __restrict__ g2, const float* __restrict__ bt2,
    const float* __restrict__ ng, const float* __restrict__ nb,
    const float* __restrict__ dWl, float* __restrict__ score) {
    __shared__ float sp[8 * DD];
    __shared__ float sdW[DD * CC];
    __shared__ float ss[GG * CC];      // 4 KB
    __shared__ float zA[64][DD];       // 8 KB
    __shared__ float z2loc[8][DD];     // 1 KB

    const int tid = threadIdx.x;

    if (tid < DD) {
        sp[0 * DD + tid] = b1[tid];
        sp[1 * DD + tid] = g1[tid];
        sp[2 * DD + tid] = bt1[tid];
        sp[3 * DD + tid] = b2[tid];
        sp[4 * DD + tid] = g2[tid];
        sp[5 * DD + tid] = bt2[tid];
        sp[6 * DD + tid] = ng[tid];
        sp[7 * DD + tid] = nb[tid];
    }
    if (tid < DD * CC) sdW[tid] = dWl[tid];
    for (int i = tid; i < GG * CC; i += 256) ss[i] = 0.f;

    const float invs = 1.0f / sqrtf(1.001f);   // BN: mean=0, var=1, eps=1e-3
    const int base = blockIdx.x * 64;

    // ---- phase 1: wave-cooperative gather ----
    {
        const int wav = tid >> 6;      // wave 0..3, owns nodes wav*16..+15
        const int lid = tid & 63;
        const int sub = lid >> 3;      // edge slot 0..7
        const int sl  = lid & 7;       // dim slice 0..7 (4 halves each)

        for (int s = 0; s < 16; ++s) {
            const int local = wav * 16 + s;
            const int n = base + local;
            if (n >= NN) break;        // uniform across the wave
            const int e0 = row_ptr[n];
            const int e1 = row_ptr[n + 1];
            float a0 = 0.f, a1 = 0.f, a2 = 0.f, a3 = 0.f;
            for (int t = e0; t < e1; t += 8) {
                const int ee = t + sub;
                const bool ok = ee < e1;
                const int ix = csr_src[ok ? ee : (e1 - 1)];
                const uint2 raw = *reinterpret_cast<const uint2*>(
                    h_in + ((size_t)ix * DD + sl * 4));
                const float2 f01 =
                    __half22float2(*reinterpret_cast<const __half2*>(&raw.x));
                const float2 f23 =
                    __half22float2(*reinterpret_cast<const __half2*>(&raw.y));
                if (ok) { a0 += f01.x; a1 += f01.y; a2 += f23.x; a3 += f23.y; }
            }
            #pragma unroll
            for (int off = 8; off < 64; off <<= 1) {
                a0 += __shfl_xor(a0, off, 64);
                a1 += __shfl_xor(a1, off, 64);
                a2 += __shfl_xor(a2, off, 64);
                a3 += __shfl_xor(a3, off, 64);
            }
            if (lid < 8) {             // add self row, write zA row (f32)
                const uint2 sraw = *reinterpret_cast<const uint2*>(
                    h_in + ((size_t)n * DD + sl * 4));
                const float2 s01 =
                    __half22float2(*reinterpret_cast<const __half2*>(&sraw.x));
                const float2 s23 =
                    __half22float2(*reinterpret_cast<const __half2*>(&sraw.y));
                float4 r;
                r.x = a0 + s01.x; r.y = a1 + s01.y;
                r.z = a2 + s23.x; r.w = a3 + s23.y;
                *reinterpret_cast<float4*>(&zA[local][sl * 4]) = r;
            }
        }
    }
    __syncthreads();

    // ---- phase 2: MLP + fused pool (no barriers; z2loc within one wave) ----
    const int j = tid >> 5;            // group 0..7
    const int d = tid & 31;
    for (int s = 0; s < 8; ++s) {
        const int local = j * 8 + s;
        const int n = base + local;
        if (n >= NN) break;            // uniform within the 32-lane group

        float a1 = sp[0 * DD + d];
        #pragma unroll
        for (int kk = 0; kk < DD; kk += 4) {
            const float4 zv = *reinterpret_cast<const float4*>(&zA[local][kk]);
            a1 += zv.x * W1[(kk + 0) * DD + d] + zv.y * W1[(kk + 1) * DD + d] +
                  zv.z * W1[(kk + 2) * DD + d] + zv.w * W1[(kk + 3) * DD + d];
        }
        float v = fmaxf(a1 * (sp[1 * DD + d] * invs) + sp[2 * DD + d], 0.f);
        z2loc[j][d] = v;               // within-wave exchange (in-order LDS)

        float a2 = sp[3 * DD + d];
        #pragma unroll
        for (int kk = 0; kk < DD; kk += 4) {
            const float4 zv = *reinterpret_cast<const float4*>(&z2loc[j][kk]);
            a2 += zv.x * W2[(kk + 0) * DD + d] + zv.y * W2[(kk + 1) * DD + d] +
                  zv.z * W2[(kk + 2) * DD + d] + zv.w * W2[(kk + 3) * DD + d];
        }
        float w = fmaxf(a2 * (sp[4 * DD + d] * invs) + sp[5 * DD + d], 0.f);
        w = fmaxf(w * (sp[6 * DD + d] * invs) + sp[7 * DD + d], 0.f);
        h_out[(size_t)n * DD + d] = __float2half_rn(w);

        float p0 = w * sdW[d * CC + 0];
        float p1 = w * sdW[d * CC + 1];
        #pragma unroll
        for (int off = 16; off > 0; off >>= 1) {
            p0 += __shfl_xor(p0, off, 32);
            p1 += __shfl_xor(p1, off, 32);
        }
        if (d == 0) {
            int g = batch[n];
            atomicAdd(&ss[g * CC + 0], p0);
            atomicAdd(&ss[g * CC + 1], p1);
        }
    }
    __syncthreads();

    for (int i = tid; i < GG * CC; i += 256) {
        float v = ss[i];
        if (v != 0.f) atomicAdd(&score[i], v);
    }
}

__global__ void softmax_kernel(const float* __restrict__ score,
                               const float* __restrict__ db,
                               float* __restrict__ out) {
    int g = blockIdx.x * blockDim.x + threadIdx.x;
    if (g >= GG) return;
    float bs0 = 0.f, bs1 = 0.f;
    #pragma unroll
    for (int i = 0; i <= NLAYERS; ++i) {
        bs0 += db[i * CC + 0];
        bs1 += db[i * CC + 1];
    }
    float s0 = score[g * CC + 0] + bs0;
    float s1 = score[g * CC + 1] + bs1;
    float m = fmaxf(s0, s1);
    float e0 = expf(s0 - m), e1 = expf(s1 - m);
    float inv = 1.f / (e0 + e1);
    out[g * CC + 0] = e0 * inv;
    out[g * CC + 1] = e1 * inv;
}

extern "C" void kernel_launch(void* const* d_in, const int* in_sizes, int n_in,
                              void* d_out, int out_size, void* d_ws, size_t ws_size,
                              hipStream_t stream) {
    (void)in_sizes; (void)n_in; (void)out_size; (void)ws_size;

    const float* node_emb = (const float*)d_in[0];
    const int*   ei       = (const int*)d_in[1];
    const int*   batch    = (const int*)d_in[2];
    const float* W1       = (const float*)d_in[3];
    const float* b1       = (const float*)d_in[4];
    const float* g1       = (const float*)d_in[5];
    const float* bt1      = (const float*)d_in[6];
    const float* W2       = (const float*)d_in[7];
    const float* b2       = (const float*)d_in[8];
    const float* g2       = (const float*)d_in[9];
    const float* bt2      = (const float*)d_in[10];
    const float* ng       = (const float*)d_in[11];
    const float* nb       = (const float*)d_in[12];
    const float* dW       = (const float*)d_in[13];
    const float* db       = (const float*)d_in[14];
    float* out = (float*)d_out;

    // workspace layout. part[] (9.63MB) aliases [hB16|hC16] (12.8MB): part is
    // consumed by lcsr before pool_cvt writes hC16 / layer 1 writes hB16.
    __half* hA16   = (__half*)d_ws;                   // [NN][DD] 6.4MB
    __half* hB16   = hA16 + (size_t)NN * DD;          // [NN][DD] 6.4MB
    __half* hC16   = hB16 + (size_t)NN * DD;          // [NN][DD] 6.4MB (cvt out)
    unsigned* part = (unsigned*)hB16;                 // [NBUK][CAP] alias
    float* score   = (float*)(hC16 + (size_t)NN * DD);// [GG][CC]
    int* row_ptr   = (int*)(score + GG * CC);         // [NN+1]
    int* csr_src   = row_ptr + NN + 2;                // [EE] 6.4MB (+pad)
    int* gcur      = csr_src + EE + 16;               // [256]
    int* bbase     = gcur + 256;                      // [256]

    hipMemsetAsync(gcur, 0, 256 * sizeof(int), stream);
    hipMemsetAsync(score, 0, GG * CC * sizeof(float), stream);

    // CSR build (cache-local)
    part_kernel<<<NPART, 256, 0, stream>>>(ei, gcur, part);
    bscan_kernel<<<1, 64, 0, stream>>>(gcur, bbase, row_ptr);
    lcsr_kernel<<<NBUK, BW, 0, stream>>>(part, gcur, bbase, row_ptr, csr_src);

    // level-0 readout + fp16 working copy, single pass (after lcsr: alias)
    pool_cvt_kernel<<<(NN + 511) / 512, 256, 0, stream>>>(
        node_emb, batch, dW, score, hC16);

    const int layerGrid = (NN + 63) / 64;             // 1563
    const __half* cur_in = hC16;
    __half* bufs[2] = {hA16, hB16};
    for (int i = 0; i < NLAYERS; ++i) {
        __half* o = bufs[i & 1];
        layer_kernel<<<layerGrid, 256, 0, stream>>>(
            cur_in, o, row_ptr, csr_src, batch,
            W1 + (size_t)i * DD * DD, b1 + i * DD, g1 + i * DD, bt1 + i * DD,
            W2 + (size_t)i * DD * DD, b2 + i * DD, g2 + i * DD, bt2 + i * DD,
            ng + i * DD, nb + i * DD,
            dW + (size_t)(i + 1) * DD * CC, score);
        cur_in = o;
    }

    softmax_kernel<<<(GG + 255) / 256, 256, 0, stream>>>(score, db, out);
}